// Round 1
// 99.393 us; speedup vs baseline: 1.1208x; 1.1208x over previous
//
#include <hip/hip_runtime.h>

// AugmentedTripletLoss on MI355X.
// inputs [8192,128] f32, targets [8192] int, center [16,128] f32 -> scalar loss.
//
// v3: class-compare folded into the GEMM via a one-hot +-s augmentation
// (K 128->192, s=128): same-class pairs get dist2 += 32768, so the epilogue
// is branchless fmaf+max+min (3 VALU/elem vs 6 with cmp+cndmask).
// pairdist restructured: 256 rows/block (4 waves x 64 rows), 512-col strips,
// B tile (16 cols x 384 B) staged to LDS once per tile via global_load_lds
// with a both-sides XOR swizzle (T21) -> L2 traffic 402 MB -> ~150 MB.
// prep_centers fused into prep (each block renormalizes the 8 KB center).

#define N_ROWS 8192
#define DIM 128
#define KDIM 192          // 128 data dims + 64 one-hot class dims
#define ROWB 384          // KDIM * 2 bytes (bf16)
#define NPROTO 16
#define MARGIN_F 1.0f
#define EPS_F 1e-12f
#define BIAS_F 32768.0f   // 2*s^2 with s=128 (exact in bf16: 0x4300)

typedef __attribute__((ext_vector_type(8))) short short8;   // 8 bf16 = 4 VGPRs
typedef __attribute__((ext_vector_type(4))) float float4v;  // MFMA acc
typedef __attribute__((ext_vector_type(4))) unsigned uint4v;

static __device__ __forceinline__ unsigned f2bf(float f) {
  // round-to-nearest-even bf16 (no NaN expected in this data)
  unsigned u = __float_as_uint(f);
  u += 0x7fffu + ((u >> 16) & 1u);
  return u >> 16;
}

static __device__ __forceinline__ void gload_lds16(const void* g, void* l) {
  __builtin_amdgcn_global_load_lds(
      (const __attribute__((address_space(1))) unsigned*)g,
      (__attribute__((address_space(3))) unsigned*)l, 16, 0, 0);
}

// 512 blocks x 16 rows. Fuses center normalization (redundant per block, 8 KB)
// + row prep: bf16 pack (data + one-hot), ||x||^2, min dist-to-center.
__global__ void prep_kernel(const float* __restrict__ x,
                            const float* __restrict__ center,
                            const int* __restrict__ tgt,
                            char* __restrict__ xbf,
                            float* __restrict__ sq,
                            float* __restrict__ mindc,
                            float* __restrict__ out) {
  __shared__ float scn[NPROTO * DIM];  // normalized prototypes, 8 KB
  int tid = threadIdx.x;
  if (blockIdx.x == 0 && tid == 0) out[0] = 0.0f;  // zero loss accumulator
  int rloc = tid >> 4, l = tid & 15;
  {
    float v[8];
    float ss = 0.f;
#pragma unroll
    for (int j = 0; j < 8; ++j) {
      v[j] = center[rloc * DIM + l * 8 + j];
      ss += v[j] * v[j];
    }
    // 16-lane groups are contiguous in the wave -> masks 1..8 stay in-group
#pragma unroll
    for (int m = 1; m < 16; m <<= 1) ss += __shfl_xor(ss, m, 64);
    float inv = 1.0f / sqrtf(ss);
#pragma unroll
    for (int j = 0; j < 8; ++j) scn[rloc * DIM + l * 8 + j] = v[j] * inv;
  }
  __syncthreads();

  int row = blockIdx.x * 16 + rloc;
  float4 v0 = ((const float4*)x)[row * 32 + l * 2];
  float4 v1 = ((const float4*)x)[row * 32 + l * 2 + 1];
  float ss = v0.x * v0.x + v0.y * v0.y + v0.z * v0.z + v0.w * v0.w +
             v1.x * v1.x + v1.y * v1.y + v1.z * v1.z + v1.w * v1.w;
  float dots[NPROTO];
#pragma unroll
  for (int p = 0; p < NPROTO; ++p) {
    const float* c = &scn[p * DIM + l * 8];
    dots[p] = v0.x * c[0] + v0.y * c[1] + v0.z * c[2] + v0.w * c[3] +
              v1.x * c[4] + v1.y * c[5] + v1.z * c[6] + v1.w * c[7];
  }
#pragma unroll
  for (int m = 1; m < 16; m <<= 1) {
    ss += __shfl_xor(ss, m, 64);
#pragma unroll
    for (int p = 0; p < NPROTO; ++p) dots[p] += __shfl_xor(dots[p], m, 64);
  }
  // data dims: row-major bf16, 384 B/row (first 256 B)
  uint4 pk;
  pk.x = f2bf(v0.x) | (f2bf(v0.y) << 16);
  pk.y = f2bf(v0.z) | (f2bf(v0.w) << 16);
  pk.z = f2bf(v1.x) | (f2bf(v1.y) << 16);
  pk.w = f2bf(v1.z) | (f2bf(v1.w) << 16);
  *(uint4*)(xbf + (size_t)row * ROWB + l * 16) = pk;
  // one-hot class dims (bytes 256..383): -128 (0xC300) at class slot.
  // B side uses the stored -s; A side flips sign in-register -> product -s^2.
  int cls = tgt[row];
  if (l < 8) {
    unsigned wv = (cls & 1) ? 0xC3000000u : 0x0000C300u;  // bf16 -128
    uint4 oh;
    oh.x = ((cls >> 1) == (l * 4 + 0)) ? wv : 0u;
    oh.y = ((cls >> 1) == (l * 4 + 1)) ? wv : 0u;
    oh.z = ((cls >> 1) == (l * 4 + 2)) ? wv : 0u;
    oh.w = ((cls >> 1) == (l * 4 + 3)) ? wv : 0u;
    *(uint4*)(xbf + (size_t)row * ROWB + 256 + l * 16) = oh;
  }
  if (l == 0) {
    float mind2 = INFINITY;
#pragma unroll
    for (int p = 0; p < NPROTO; ++p)
      mind2 = fminf(mind2, ss + 1.0f - 2.0f * dots[p]);  // cn is unit-norm
    sq[row] = ss;
    mindc[row] = fmaxf(sqrtf(fmaxf(mind2, 0.0f)), EPS_F);
  }
}

// Grid: 32 row-groups (256 rows) x 16 strips (512 cols) = 512 blocks.
// Block = 4 waves; wave w owns rows rowbase+w*64..+63 (4 row-tiles), all
// waves share the LDS-staged B tile (16 cols x 384 B, double-buffered).
// v' = sq_c - 2*dot' tracked; one-hot bias makes positives = v + 32768.
__global__ __launch_bounds__(256, 2) void
pairdist_kernel(const char* __restrict__ xbf, const float* __restrict__ sq,
                float* __restrict__ pmax, float* __restrict__ pmin) {
  __shared__ __align__(16) char bl[2][6144];  // 2 x (16 cols x 384 B)
  const int bid = blockIdx.x;
  const int rg = bid >> 4;
  const int strip = bid & 15;
  const int wave = threadIdx.x >> 6, lane = threadIdx.x & 63;
  const int q = lane >> 4, l16 = lane & 15;
  const int rowbase = rg * 256 + wave * 64;
  const int stripbase = strip * 512;

  // Staging: LDS dest is linear (base+lane*16, T21), so the XOR swizzle
  // o' = o ^ ((col&7)<<4) is applied to the per-lane GLOBAL source address
  // here and to the ds_read address below (same involution both sides).
  const int slot = wave * 64 + lane;
  const char* const srcstrip = xbf + (size_t)stripbase * ROWB;
  int op0 = slot * 16;  // round 0: slots 0..255 -> LDS bytes 0..4095
  int c0 = op0 / ROWB;
  const int soff0 = c0 * ROWB + ((op0 - c0 * ROWB) ^ ((c0 & 7) << 4));
  int op1 = 4096 + slot * 16;  // round 1 (waves 0,1): LDS bytes 4096..6143
  int c1 = op1 / ROWB;
  const int soff1 = c1 * ROWB + ((op1 - c1 * ROWB) ^ ((c1 & 7) << 4));

  auto stage = [&](int t, char* buf) {
    const char* s = srcstrip + (size_t)t * 6144;  // 16 cols * 384 B per tile
    gload_lds16(s + soff0, buf + wave * 1024);
    if (wave < 2) gload_lds16(s + soff1, buf + 4096 + wave * 1024);
  };

  stage(0, bl[0]);  // prefetch tile 0 under the A-fragment loads

  // A-frags: A[m=l16][k=q*8+j], 4 row-tiles x 6 k-chunks (last 2 = one-hot,
  // stored -s -> flip sign to +s so the MFMA product is -s^2).
  short8 a[4][6];
#pragma unroll
  for (int rt = 0; rt < 4; ++rt) {
    const char* ar = xbf + (size_t)(rowbase + rt * 16 + l16) * ROWB + q * 16;
#pragma unroll
    for (int kc = 0; kc < 6; ++kc) a[rt][kc] = *(const short8*)(ar + kc * 64);
#pragma unroll
    for (int kc = 4; kc < 6; ++kc) {
      uint4v u = __builtin_bit_cast(uint4v, a[rt][kc]);
      u ^= 0x80008000u;
      a[rt][kc] = __builtin_bit_cast(short8, u);
    }
  }

  int roff[6];  // swizzled LDS read offsets (t-invariant)
#pragma unroll
  for (int kc = 0; kc < 6; ++kc)
    roff[kc] = (l16 * ROWB + kc * 64 + q * 16) ^ ((l16 & 7) << 4);

  float maxp[16], minn[16];
#pragma unroll
  for (int i = 0; i < 16; ++i) {
    maxp[i] = -INFINITY;
    minn[i] = INFINITY;
  }

  auto tile_step = [&](int t, const char* cur, char* nxt) {
    __syncthreads();  // drains own global_load_lds (vmcnt) + syncs buffers
    if (t + 1 < 32) stage(t + 1, nxt);  // async prefetch overlaps compute
    float sqc = sq[stripbase + t * 16 + l16];
    short8 b[6];
#pragma unroll
    for (int kc = 0; kc < 6; ++kc) b[kc] = *(const short8*)(cur + roff[kc]);
    float4v acc[4];
#pragma unroll
    for (int rt = 0; rt < 4; ++rt) acc[rt] = (float4v){0.f, 0.f, 0.f, 0.f};
#pragma unroll
    for (int kc = 0; kc < 6; ++kc)
#pragma unroll
      for (int rt = 0; rt < 4; ++rt)  // 4 independent acc chains
        acc[rt] = __builtin_amdgcn_mfma_f32_16x16x32_bf16(a[rt][kc], b[kc],
                                                          acc[rt], 0, 0, 0);
    // C/D layout: col = lane&15, row = q*4 + reg (m89-verified).
    // Branchless: positives carry +32768 bias, so max/min need no compare.
#pragma unroll
    for (int rt = 0; rt < 4; ++rt)
#pragma unroll
      for (int r = 0; r < 4; ++r) {
        float v = fmaf(-2.0f, acc[rt][r], sqc);  // dist2 = sq_row + v (- bias)
        int idx = rt * 4 + r;
        maxp[idx] = fmaxf(maxp[idx], v);
        minn[idx] = fminf(minn[idx], v);
      }
  };

#pragma unroll 1
  for (int tp = 0; tp < 16; ++tp) {
    tile_step(2 * tp, bl[0], bl[1]);
    tile_step(2 * tp + 1, bl[1], bl[0]);
  }

  // reduce across the 16 lanes of each quad (masks 1..8 stay in-group)
#pragma unroll
  for (int m = 1; m < 16; m <<= 1)
#pragma unroll
    for (int i = 0; i < 16; ++i) {
      maxp[i] = fmaxf(maxp[i], __shfl_xor(maxp[i], m, 64));
      minn[i] = fminf(minn[i], __shfl_xor(minn[i], m, 64));
    }
  // waves own disjoint rows -> no cross-wave reduce; direct scattered store
  if (l16 == 0) {
    float* pM = pmax + (size_t)strip * N_ROWS + rowbase + q * 4;
    float* pm = pmin + (size_t)strip * N_ROWS + rowbase + q * 4;
#pragma unroll
    for (int rt = 0; rt < 4; ++rt)
#pragma unroll
      for (int r = 0; r < 4; ++r) {
        pM[rt * 16 + r] = maxp[rt * 4 + r];
        pm[rt * 16 + r] = minn[rt * 4 + r];
      }
  }
}

__global__ void finalize_kernel(const float* __restrict__ pmax,
                                const float* __restrict__ pmin,
                                const float* __restrict__ sq,
                                const float* __restrict__ mindc,
                                float* __restrict__ out) {
  __shared__ float wsum[4];
  int i = blockIdx.x * 256 + threadIdx.x;  // 32 blocks x 256 = 8192 rows
  float maxv = -INFINITY, minv = INFINITY;
#pragma unroll
  for (int s = 0; s < 16; ++s) {
    maxv = fmaxf(maxv, pmax[s * N_ROWS + i]);
    minv = fminf(minv, pmin[s * N_ROWS + i]);
  }
  float si = sq[i];
  float dap = sqrtf(fmaxf(si + (maxv - BIAS_F), EPS_F));  // un-bias positives
  // negatives are unbiased (< ~2000); if none exist anywhere, minv is the
  // biased positive min (~32768) -> fall back to dap + margin
  float dan = (minv > 16384.0f) ? (dap + MARGIN_F)
                                : sqrtf(fmaxf(si + minv, EPS_F));
  dan = fminf(dan, mindc[i]);
  float c = fmaxf(dap - dan + MARGIN_F, 0.0f) * (1.0f / (float)N_ROWS);
#pragma unroll
  for (int m = 1; m < 64; m <<= 1) c += __shfl_xor(c, m, 64);
  int lane = threadIdx.x & 63, wv = threadIdx.x >> 6;
  if (lane == 0) wsum[wv] = c;
  __syncthreads();
  if (threadIdx.x == 0) atomicAdd(out, wsum[0] + wsum[1] + wsum[2] + wsum[3]);
}

extern "C" void kernel_launch(void* const* d_in, const int* in_sizes, int n_in,
                              void* d_out, int out_size, void* d_ws, size_t ws_size,
                              hipStream_t stream) {
  const float* inputs = (const float*)d_in[0];
  const int* targets = (const int*)d_in[1];  // per harness: integer -> const int*
  const float* center = (const float*)d_in[2];
  char* ws = (char*)d_ws;
  // ws layout (all 256B-aligned):
  char* xbf    = ws;                       // 8192*384 B bf16+onehot = 3 MB
  float* sq    = (float*)(ws + 3145728);   // 8192 f32 = 32 KB
  float* mindc = (float*)(ws + 3178496);   // 8192 f32 = 32 KB
  float* pmax  = (float*)(ws + 3211264);   // 16*8192 f32 = 512 KB
  float* pmin  = (float*)(ws + 3735552);   // 16*8192 f32 = 512 KB
  float* out   = (float*)d_out;

  prep_kernel<<<512, 256, 0, stream>>>(inputs, center, targets, xbf, sq, mindc, out);
  pairdist_kernel<<<512, 256, 0, stream>>>(xbf, sq, pmax, pmin);
  finalize_kernel<<<32, 256, 0, stream>>>(pmax, pmin, sq, mindc, out);
}

// Round 2
// 92.988 us; speedup vs baseline: 1.1980x; 1.0689x over previous
//
#include <hip/hip_runtime.h>

// AugmentedTripletLoss on MI355X.
// inputs [8192,128] f32, targets [8192] int, center [16,128] f32 -> scalar loss.
//
// v4: pairdist re-scheduled. v3 staged 16 cols (6 KB) per barrier; the
// __syncthreads vmcnt(0) drain exposed ~full L2 latency every step (32x).
// Now: 64-col stages (24 KB, 2x double-buffered = 48 KB LDS), prefetch for
// stage s+1 issued right after the barrier, then 4 sub-steps (~1200 cy) of
// MFMA+epilogue hide the load latency; 8 barriers/block instead of 32.
// Pipe floors per CU: LDS 402 MB -> 7.7 us (binding), MFMA 3.1, VALU ~3.
// Unchanged from v3 (verified): one-hot +-s class bias folded into GEMM
// (K=192, branchless epilogue), both-sides XOR swizzle (T21), prep fusion.

#define N_ROWS 8192
#define DIM 128
#define KDIM 192          // 128 data dims + 64 one-hot class dims
#define ROWB 384          // KDIM * 2 bytes (bf16)
#define NPROTO 16
#define MARGIN_F 1.0f
#define EPS_F 1e-12f
#define BIAS_F 32768.0f   // 2*s^2 with s=128 (exact in bf16: 0x4300)

typedef __attribute__((ext_vector_type(8))) short short8;   // 8 bf16 = 4 VGPRs
typedef __attribute__((ext_vector_type(4))) float float4v;  // MFMA acc
typedef __attribute__((ext_vector_type(4))) unsigned uint4v;

static __device__ __forceinline__ unsigned f2bf(float f) {
  // round-to-nearest-even bf16 (no NaN expected in this data)
  unsigned u = __float_as_uint(f);
  u += 0x7fffu + ((u >> 16) & 1u);
  return u >> 16;
}

static __device__ __forceinline__ void gload_lds16(const void* g, void* l) {
  __builtin_amdgcn_global_load_lds(
      (const __attribute__((address_space(1))) unsigned*)g,
      (__attribute__((address_space(3))) unsigned*)l, 16, 0, 0);
}

// 512 blocks x 16 rows. Fuses center normalization (redundant per block, 8 KB)
// + row prep: bf16 pack (data + one-hot), ||x||^2, min dist-to-center.
__global__ void prep_kernel(const float* __restrict__ x,
                            const float* __restrict__ center,
                            const int* __restrict__ tgt,
                            char* __restrict__ xbf,
                            float* __restrict__ sq,
                            float* __restrict__ mindc,
                            float* __restrict__ out) {
  __shared__ float scn[NPROTO * DIM];  // normalized prototypes, 8 KB
  int tid = threadIdx.x;
  if (blockIdx.x == 0 && tid == 0) out[0] = 0.0f;  // zero loss accumulator
  int rloc = tid >> 4, l = tid & 15;
  {
    float v[8];
    float ss = 0.f;
#pragma unroll
    for (int j = 0; j < 8; ++j) {
      v[j] = center[rloc * DIM + l * 8 + j];
      ss += v[j] * v[j];
    }
    // 16-lane groups are contiguous in the wave -> masks 1..8 stay in-group
#pragma unroll
    for (int m = 1; m < 16; m <<= 1) ss += __shfl_xor(ss, m, 64);
    float inv = 1.0f / sqrtf(ss);
#pragma unroll
    for (int j = 0; j < 8; ++j) scn[rloc * DIM + l * 8 + j] = v[j] * inv;
  }
  __syncthreads();

  int row = blockIdx.x * 16 + rloc;
  float4 v0 = ((const float4*)x)[row * 32 + l * 2];
  float4 v1 = ((const float4*)x)[row * 32 + l * 2 + 1];
  float ss = v0.x * v0.x + v0.y * v0.y + v0.z * v0.z + v0.w * v0.w +
             v1.x * v1.x + v1.y * v1.y + v1.z * v1.z + v1.w * v1.w;
  float dots[NPROTO];
#pragma unroll
  for (int p = 0; p < NPROTO; ++p) {
    const float* c = &scn[p * DIM + l * 8];
    dots[p] = v0.x * c[0] + v0.y * c[1] + v0.z * c[2] + v0.w * c[3] +
              v1.x * c[4] + v1.y * c[5] + v1.z * c[6] + v1.w * c[7];
  }
#pragma unroll
  for (int m = 1; m < 16; m <<= 1) {
    ss += __shfl_xor(ss, m, 64);
#pragma unroll
    for (int p = 0; p < NPROTO; ++p) dots[p] += __shfl_xor(dots[p], m, 64);
  }
  // data dims: row-major bf16, 384 B/row (first 256 B)
  uint4 pk;
  pk.x = f2bf(v0.x) | (f2bf(v0.y) << 16);
  pk.y = f2bf(v0.z) | (f2bf(v0.w) << 16);
  pk.z = f2bf(v1.x) | (f2bf(v1.y) << 16);
  pk.w = f2bf(v1.z) | (f2bf(v1.w) << 16);
  *(uint4*)(xbf + (size_t)row * ROWB + l * 16) = pk;
  // one-hot class dims (bytes 256..383): -128 (0xC300) at class slot.
  // B side uses the stored -s; A side flips sign in-register -> product -s^2.
  int cls = tgt[row];
  if (l < 8) {
    unsigned wv = (cls & 1) ? 0xC3000000u : 0x0000C300u;  // bf16 -128
    uint4 oh;
    oh.x = ((cls >> 1) == (l * 4 + 0)) ? wv : 0u;
    oh.y = ((cls >> 1) == (l * 4 + 1)) ? wv : 0u;
    oh.z = ((cls >> 1) == (l * 4 + 2)) ? wv : 0u;
    oh.w = ((cls >> 1) == (l * 4 + 3)) ? wv : 0u;
    *(uint4*)(xbf + (size_t)row * ROWB + 256 + l * 16) = oh;
  }
  if (l == 0) {
    float mind2 = INFINITY;
#pragma unroll
    for (int p = 0; p < NPROTO; ++p)
      mind2 = fminf(mind2, ss + 1.0f - 2.0f * dots[p]);  // cn is unit-norm
    sq[row] = ss;
    mindc[row] = fmaxf(sqrtf(fmaxf(mind2, 0.0f)), EPS_F);
  }
}

// Grid: 32 row-groups (256 rows) x 16 strips (512 cols) = 512 blocks.
// Block = 4 waves; wave w owns rows rowbase+w*64..+63 (4 row-tiles), all
// waves share the LDS-staged B tile. Stage = 64 cols x 384 B = 24 KB,
// double-buffered; 8 stages x 4 sub-steps per strip.
// v' = sq_c - 2*dot' tracked; one-hot bias makes positives = v + 32768.
__global__ __launch_bounds__(256, 2) void
pairdist_kernel(const char* __restrict__ xbf, const float* __restrict__ sq,
                float* __restrict__ pmax, float* __restrict__ pmin) {
  __shared__ __align__(16) char bl[2][24576];  // 2 x (64 cols x 384 B)
  const int bid = blockIdx.x;
  const int rg = bid >> 4;
  const int strip = bid & 15;
  const int wave = threadIdx.x >> 6, lane = threadIdx.x & 63;
  const int q = lane >> 4, l16 = lane & 15;
  const int rowbase = rg * 256 + wave * 64;
  const int stripbase = strip * 512;

  // Staging: 6 rounds x 4 KB (all 4 waves). LDS dest is linear
  // (wave-uniform base + lane*16, T21); the XOR swizzle o' = o ^ ((col&7)<<4)
  // is applied to the per-lane GLOBAL source address here and to the ds_read
  // address below (same involution both sides).
  const int slot = wave * 64 + lane;
  const char* const srcstrip = xbf + (size_t)stripbase * ROWB;
  int soff[6];
#pragma unroll
  for (int r = 0; r < 6; ++r) {
    int o = r * 4096 + slot * 16;
    int c = o / ROWB;
    soff[r] = c * ROWB + ((o - c * ROWB) ^ ((c & 7) << 4));
  }

  auto stage = [&](int s, char* buf) {
    const char* g = srcstrip + (size_t)s * 24576;  // 64 cols * 384 B per stage
#pragma unroll
    for (int r = 0; r < 6; ++r)
      gload_lds16(g + soff[r], buf + r * 4096 + wave * 1024);
  };

  stage(0, bl[0]);  // prefetch stage 0 under the A-fragment loads

  // A-frags: A[m=l16][k=q*8+j], 4 row-tiles x 6 k-chunks (last 2 = one-hot,
  // stored -s -> flip sign to +s so the MFMA product is -s^2).
  short8 a[4][6];
#pragma unroll
  for (int rt = 0; rt < 4; ++rt) {
    const char* ar = xbf + (size_t)(rowbase + rt * 16 + l16) * ROWB + q * 16;
#pragma unroll
    for (int kc = 0; kc < 6; ++kc) a[rt][kc] = *(const short8*)(ar + kc * 64);
#pragma unroll
    for (int kc = 4; kc < 6; ++kc) {
      uint4v u = __builtin_bit_cast(uint4v, a[rt][kc]);
      u ^= 0x80008000u;
      a[rt][kc] = __builtin_bit_cast(short8, u);
    }
  }

  // Swizzled LDS read offsets. Sub-step ss reads buffer col cc = ss*16+l16;
  // cc&7 == l16&7, so the ss term (ss*6144) is additive outside the XOR.
  int roffb[6];
#pragma unroll
  for (int kc = 0; kc < 6; ++kc)
    roffb[kc] = (l16 * ROWB + kc * 64 + q * 16) ^ ((l16 & 7) << 4);

  float maxp[16], minn[16];
#pragma unroll
  for (int i = 0; i < 16; ++i) {
    maxp[i] = -INFINITY;
    minn[i] = INFINITY;
  }

#pragma unroll 1
  for (int s = 0; s < 8; ++s) {
    __syncthreads();  // buf[s&1] staged (vmcnt drain) + prev compute done
    if (s + 1 < 8) stage(s + 1, bl[(s + 1) & 1]);  // ~1200 cy to land
    const char* cur = bl[s & 1];
    float sqs[4];  // hoisted: issued early, consumed across the stage
#pragma unroll
    for (int ss = 0; ss < 4; ++ss)
      sqs[ss] = sq[stripbase + s * 64 + ss * 16 + l16];
#pragma unroll
    for (int ss = 0; ss < 4; ++ss) {
      const char* bufp = cur + ss * 6144;
      short8 b[6];
#pragma unroll
      for (int kc = 0; kc < 6; ++kc)
        b[kc] = *(const short8*)(bufp + roffb[kc]);
      float4v acc[4];
#pragma unroll
      for (int rt = 0; rt < 4; ++rt) acc[rt] = (float4v){0.f, 0.f, 0.f, 0.f};
#pragma unroll
      for (int kc = 0; kc < 6; ++kc)
#pragma unroll
        for (int rt = 0; rt < 4; ++rt)  // 4 independent acc chains
          acc[rt] = __builtin_amdgcn_mfma_f32_16x16x32_bf16(a[rt][kc], b[kc],
                                                            acc[rt], 0, 0, 0);
      // C/D layout: col = lane&15, row = q*4 + reg (m89-verified).
      // Branchless: positives carry +32768 bias, so max/min need no compare.
#pragma unroll
      for (int rt = 0; rt < 4; ++rt)
#pragma unroll
        for (int r = 0; r < 4; ++r) {
          float v = fmaf(-2.0f, acc[rt][r], sqs[ss]);  // dist2 = sq_row + v
          int idx = rt * 4 + r;
          maxp[idx] = fmaxf(maxp[idx], v);
          minn[idx] = fminf(minn[idx], v);
        }
    }
  }

  // reduce across the 16 lanes of each quad (masks 1..8 stay in-group)
#pragma unroll
  for (int m = 1; m < 16; m <<= 1)
#pragma unroll
    for (int i = 0; i < 16; ++i) {
      maxp[i] = fmaxf(maxp[i], __shfl_xor(maxp[i], m, 64));
      minn[i] = fminf(minn[i], __shfl_xor(minn[i], m, 64));
    }
  // waves own disjoint rows -> no cross-wave reduce; direct scattered store
  if (l16 == 0) {
    float* pM = pmax + (size_t)strip * N_ROWS + rowbase + q * 4;
    float* pm = pmin + (size_t)strip * N_ROWS + rowbase + q * 4;
#pragma unroll
    for (int rt = 0; rt < 4; ++rt)
#pragma unroll
      for (int r = 0; r < 4; ++r) {
        pM[rt * 16 + r] = maxp[rt * 4 + r];
        pm[rt * 16 + r] = minn[rt * 4 + r];
      }
  }
}

__global__ void finalize_kernel(const float* __restrict__ pmax,
                                const float* __restrict__ pmin,
                                const float* __restrict__ sq,
                                const float* __restrict__ mindc,
                                float* __restrict__ out) {
  __shared__ float wsum[4];
  int i = blockIdx.x * 256 + threadIdx.x;  // 32 blocks x 256 = 8192 rows
  float maxv = -INFINITY, minv = INFINITY;
#pragma unroll
  for (int s = 0; s < 16; ++s) {
    maxv = fmaxf(maxv, pmax[s * N_ROWS + i]);
    minv = fminf(minv, pmin[s * N_ROWS + i]);
  }
  float si = sq[i];
  float dap = sqrtf(fmaxf(si + (maxv - BIAS_F), EPS_F));  // un-bias positives
  // negatives are unbiased (< ~2000); if none exist anywhere, minv is the
  // biased positive min (~32768) -> fall back to dap + margin
  float dan = (minv > 16384.0f) ? (dap + MARGIN_F)
                                : sqrtf(fmaxf(si + minv, EPS_F));
  dan = fminf(dan, mindc[i]);
  float c = fmaxf(dap - dan + MARGIN_F, 0.0f) * (1.0f / (float)N_ROWS);
#pragma unroll
  for (int m = 1; m < 64; m <<= 1) c += __shfl_xor(c, m, 64);
  int lane = threadIdx.x & 63, wv = threadIdx.x >> 6;
  if (lane == 0) wsum[wv] = c;
  __syncthreads();
  if (threadIdx.x == 0) atomicAdd(out, wsum[0] + wsum[1] + wsum[2] + wsum[3]);
}

extern "C" void kernel_launch(void* const* d_in, const int* in_sizes, int n_in,
                              void* d_out, int out_size, void* d_ws, size_t ws_size,
                              hipStream_t stream) {
  const float* inputs = (const float*)d_in[0];
  const int* targets = (const int*)d_in[1];  // per harness: integer -> const int*
  const float* center = (const float*)d_in[2];
  char* ws = (char*)d_ws;
  // ws layout (all 256B-aligned):
  char* xbf    = ws;                       // 8192*384 B bf16+onehot = 3 MB
  float* sq    = (float*)(ws + 3145728);   // 8192 f32 = 32 KB
  float* mindc = (float*)(ws + 3178496);   // 8192 f32 = 32 KB
  float* pmax  = (float*)(ws + 3211264);   // 16*8192 f32 = 512 KB
  float* pmin  = (float*)(ws + 3735552);   // 16*8192 f32 = 512 KB
  float* out   = (float*)d_out;

  prep_kernel<<<512, 256, 0, stream>>>(inputs, center, targets, xbf, sq, mindc, out);
  pairdist_kernel<<<512, 256, 0, stream>>>(xbf, sq, pmax, pmin);
  finalize_kernel<<<32, 256, 0, stream>>>(pmax, pmin, sq, mindc, out);
}